// Round 8
// baseline (148.624 us; speedup 1.0000x reference)
//
#include <hip/hip_runtime.h>

// DepthDeformConv — round 16: single fused kernel (prep -> spin-sync -> main).
//   Main pinned at ~43-44us across 7 structural theories (corner source,
//   barriers, pipelining, I$, TLP, VALU) with all pipes <20% busy; the only
//   real wins came from removing rounds/launches (r10 -5.3, r12 -4.2).
//   Remaining attackable serial overhead: the prep dispatch + inter-kernel
//   gap. 256 blocks x 1024thr @ 155KB LDS -> provably 1 block/CU, all
//   co-resident -> safe device-scope flag sync without cooperative launch.
//   Phase1: each block transposes 2 NCHW rows -> NHWC bf16 (LDS tile
//   aliased onto the window buffer); blocks 0-4 repack weights. Release
//   atomicAdd -> acquire spin (flag zeroed by a 4B hipMemsetAsync, graph
//   capturable). sten staging hoisted BEFORE the spin (independent of
//   prep). Then the r15 body verbatim. Window reads now L2-warm.

typedef __attribute__((ext_vector_type(8))) short bf16x8;
typedef __attribute__((ext_vector_type(4))) float f32x4;
typedef __attribute__((ext_vector_type(2))) float f32x2;
typedef __attribute__((ext_vector_type(4))) unsigned int u32x4;

#define HH 128
#define WW 128
#define CC 64
#define OO 64
#define HW (128 * 128)

__device__ __forceinline__ unsigned f32_to_bf16_rne(float f) {
    unsigned u = __float_as_uint(f);
    return (u + 0x7FFFu + ((u >> 16) & 1u)) >> 16;
}

// ---------------- fused kernel: prep phase + spin sync + sample/MFMA ----------------
__global__ __launch_bounds__(1024)
void ddc_fused16(const float* __restrict__ input,
                 unsigned short* __restrict__ nhwc,
                 const float* __restrict__ weight,
                 unsigned short* __restrict__ wT2,
                 const float* __restrict__ offset,
                 const float* __restrict__ mask,
                 const float* __restrict__ bias,
                 float* __restrict__ out,
                 int* __restrict__ flag)
{
    __shared__ u32x4 win[8192];            // 128 KB window (phase1 aliases a tile here)
    __shared__ float sten[6912];           // 27 KB: [plane 0..26][hr 0..1][x 0..127]

    const int blk0 = blockIdx.x;           // 256 blocks
    const int tid  = threadIdx.x;

    // ================= phase 1: prep (NCHW->NHWC + weight repack) =================
    {
        unsigned (*tile)[129] = (unsigned (*)[129])win;   // 64 x 129 u32 = 33 KB
        #pragma unroll
        for (int rr = 0; rr < 2; ++rr) {
            const int r = blk0 * 2 + rr;                  // 0..511 = (b,y)
            const int pb = r >> 7, py = r & 127;
            // load+convert: 64c x 128x via float4
            #pragma unroll
            for (int it = 0; it < 2; ++it) {
                const int f = it * 1024 + tid;            // 0..2047
                const int c = f >> 5, x4 = f & 31;
                const f32x4 v = *(const f32x4*)(input + ((pb * 64 + c) * 128 + py) * 128 + x4 * 4);
                tile[c][x4 * 4 + 0] = f32_to_bf16_rne(v[0]);
                tile[c][x4 * 4 + 1] = f32_to_bf16_rne(v[1]);
                tile[c][x4 * 4 + 2] = f32_to_bf16_rne(v[2]);
                tile[c][x4 * 4 + 3] = f32_to_bf16_rne(v[3]);
            }
            __syncthreads();
            {
                const int x = tid >> 3, cg = tid & 7;     // 128x * 8 channel-groups
                unsigned r0 = tile[cg * 8 + 0][x], r1 = tile[cg * 8 + 1][x];
                unsigned r2 = tile[cg * 8 + 2][x], r3 = tile[cg * 8 + 3][x];
                unsigned r4 = tile[cg * 8 + 4][x], r5 = tile[cg * 8 + 5][x];
                unsigned r6 = tile[cg * 8 + 6][x], r7 = tile[cg * 8 + 7][x];
                u32x4 pk;
                pk[0] = r0 | (r1 << 16); pk[1] = r2 | (r3 << 16);
                pk[2] = r4 | (r5 << 16); pk[3] = r6 | (r7 << 16);
                *(u32x4*)(nhwc + ((size_t)((pb * 128 + py) * 128 + x)) * 64 + cg * 8) = pk;
            }
            __syncthreads();
        }
        // weight repack on blocks 0..4
        const int d = blk0 * 1024 + tid;                  // 0..4607 valid
        if (d < 4608) {
            const int o  = d & 63;
            const int k8 = d >> 6;
            const int kt = k8 >> 3;
            const int c8 = k8 & 7;
            u32x4 pk;
            #pragma unroll
            for (int jj = 0; jj < 4; ++jj) {
                unsigned lo = f32_to_bf16_rne(weight[o * 576 + (c8 * 8 + 2 * jj)     * 9 + kt]);
                unsigned hi = f32_to_bf16_rne(weight[o * 576 + (c8 * 8 + 2 * jj + 1) * 9 + kt]);
                pk[jj] = lo | (hi << 16);
            }
            *(u32x4*)(wT2 + (size_t)d * 8) = pk;
        }
        __syncthreads();
    }

    // ---- main-block coordinates (XCD-chunked swizzle) ----
    const int blk  = (blk0 & 7) * 32 + (blk0 >> 3);
    const int b    = blk >> 6;
    const int h0   = (blk & 63) * 2;
    const int ys   = h0 - 3;               // window start row
    const int wave = tid >> 6;             // 16 waves
    const int lane = tid & 63;
    const int l15  = lane & 15;
    const int kq   = lane >> 4;
    const int hr   = wave >> 3;
    const int h    = h0 + hr;
    const int wpix = (wave & 7) * 16 + l15;

    // ---- stage offset/mask planes (independent of prep -> hides under spin) ----
    #pragma unroll
    for (int it = 0; it < 7; ++it) {
        const int f = it * 1024 + tid;                // 0..7167
        if (f < 6912) {
            const int plane = f >> 8;                 // 0..26
            const int fr    = (f >> 7) & 1;
            const int x     = f & 127;
            sten[f] = (plane < 18)
                ? offset[((b * 18 + plane)      * 128 + (h0 + fr)) * 128 + x]
                : mask  [((b * 9 + (plane - 18))* 128 + (h0 + fr)) * 128 + x];
        }
    }

    // ================= release / acquire sync (all 256 blocks co-resident) =========
    if (tid == 0) {
        __hip_atomic_fetch_add(flag, 1, __ATOMIC_RELEASE, __HIP_MEMORY_SCOPE_AGENT);
        int spins = 0;
        while (__hip_atomic_load(flag, __ATOMIC_ACQUIRE, __HIP_MEMORY_SCOPE_AGENT) < 256
               && spins < (1 << 27)) {
            __builtin_amdgcn_s_sleep(8);
            ++spins;
        }
    }
    __syncthreads();

    // ================= phase 2: window stage + taps (r15 body) =====================
    f32x4 acc[4];
    #pragma unroll
    for (int mt = 0; mt < 4; ++mt) acc[mt] = (f32x4){0.f, 0.f, 0.f, 0.f};

    const unsigned short* nb = nhwc + (size_t)b * HW * CC;
    const u32x4* wsrc = (const u32x4*)wT2;

    #pragma unroll
    for (int slot = 0; slot < 8; ++slot) {
        const int y = ys + slot;
        if (y >= 0 && y < HH) {
            const int q  = tid;                       // 0..1023 = one full row
            const int x  = q >> 3;
            const int c8 = q & 7;
            win[slot * 1024 + q] =
                *(const u32x4*)(nb + ((size_t)(y * WW + x)) * CC + ((c8 ^ (x & 7)) << 3));
        }
    }
    __syncthreads();

    #pragma unroll
    for (int kt = 0; kt < 9; ++kt) {
        const float oy = sten[(2 * kt)     * 256 + hr * 128 + wpix];
        const float ox = sten[(2 * kt + 1) * 256 + hr * 128 + wpix];
        const float m  = sten[(18 + kt)    * 256 + hr * 128 + wpix];

        const float py = (float)(h - 1 + kt / 3) + oy;
        const float px = (float)(wpix - 1 + kt % 3) + ox;
        const float y0f = floorf(py), x0f = floorf(px);
        const int y0 = (int)y0f, x0 = (int)x0f;
        const float wy = py - y0f, wx = px - x0f;
        const int y1 = y0 + 1, x1 = x0 + 1;
        const bool vy0 = (y0 >= 0) & (y0 < HH);
        const bool vy1 = (y1 >= 0) & (y1 < HH);
        const bool vx0 = (x0 >= 0) & (x0 < WW);
        const bool vx1 = (x1 >= 0) & (x1 < WW);
        const int y0c = min(max(y0, 0), HH - 1), y1c = min(max(y1, 0), HH - 1);
        const int x0c = min(max(x0, 0), WW - 1), x1c = min(max(x1, 0), WW - 1);
        const float wy1 = 1.f - wy, wx1 = 1.f - wx;
        const float c00 = (vy0 && vx0) ? wy1 * wx1 * m : 0.f;
        const float c01 = (vy0 && vx1) ? wy1 * wx  * m : 0.f;
        const float c10 = (vy1 && vx0) ? wy  * wx1 * m : 0.f;
        const float c11 = (vy1 && vx1) ? wy  * wx  * m : 0.f;

        const int s0 = y0c - ys, s1 = y1c - ys;
        const bool in0 = ((unsigned)s0 < 8u);
        const bool in1 = ((unsigned)s1 < 8u);
        const int r0 = (in0 ? s0 : 0) * 1024;
        const int r1 = (in1 ? s1 : 0) * 1024;
        const int bx0 = x0c * 8, sx0 = x0c & 7;
        const int bx1 = x1c * 8, sx1 = x1c & 7;

        const f32x2 vc00 = (f32x2){c00, c00}, vc01 = (f32x2){c01, c01};
        const f32x2 vc10 = (f32x2){c10, c10}, vc11 = (f32x2){c11, c11};

        #pragma unroll
        for (int ks = 0; ks < 2; ++ks) {
            const int ch = ks * 4 + kq;

            u32x4 w00 = win[r0 + bx0 + (ch ^ sx0)];
            u32x4 w01 = win[r0 + bx1 + (ch ^ sx1)];
            u32x4 w10 = win[r1 + bx0 + (ch ^ sx0)];
            u32x4 w11 = win[r1 + bx1 + (ch ^ sx1)];
            if (!in0) {
                w00 = *(const u32x4*)(nb + ((size_t)y0c * WW + x0c) * CC + ch * 8);
                w01 = *(const u32x4*)(nb + ((size_t)y0c * WW + x1c) * CC + ch * 8);
            }
            if (!in1) {
                w10 = *(const u32x4*)(nb + ((size_t)y1c * WW + x0c) * CC + ch * 8);
                w11 = *(const u32x4*)(nb + ((size_t)y1c * WW + x1c) * CC + ch * 8);
            }

            u32x4 pk;
            #pragma unroll
            for (int j = 0; j < 4; ++j) {
                const f32x2 A = (f32x2){__uint_as_float(w00[j] << 16),
                                        __uint_as_float(w00[j] & 0xFFFF0000u)};
                const f32x2 B = (f32x2){__uint_as_float(w01[j] << 16),
                                        __uint_as_float(w01[j] & 0xFFFF0000u)};
                const f32x2 D = (f32x2){__uint_as_float(w10[j] << 16),
                                        __uint_as_float(w10[j] & 0xFFFF0000u)};
                const f32x2 E = (f32x2){__uint_as_float(w11[j] << 16),
                                        __uint_as_float(w11[j] & 0xFFFF0000u)};
                const f32x2 S = vc00 * A + vc01 * B + vc10 * D + vc11 * E;
                unsigned r;
                asm("v_cvt_pk_bf16_f32 %0, %1, %2" : "=v"(r) : "v"(S[0]), "v"(S[1]));
                pk[j] = r;
            }
            const bf16x8 bfrag = __builtin_bit_cast(bf16x8, pk);

            const u32x4* wp = wsrc + (kt * 8 + ks * 4 + kq) * 64 + l15;
            acc[0] = __builtin_amdgcn_mfma_f32_16x16x32_bf16(
                __builtin_bit_cast(bf16x8, wp[0]),  bfrag, acc[0], 0, 0, 0);
            acc[1] = __builtin_amdgcn_mfma_f32_16x16x32_bf16(
                __builtin_bit_cast(bf16x8, wp[16]), bfrag, acc[1], 0, 0, 0);
            acc[2] = __builtin_amdgcn_mfma_f32_16x16x32_bf16(
                __builtin_bit_cast(bf16x8, wp[32]), bfrag, acc[2], 0, 0, 0);
            acc[3] = __builtin_amdgcn_mfma_f32_16x16x32_bf16(
                __builtin_bit_cast(bf16x8, wp[48]), bfrag, acc[3], 0, 0, 0);
        }
    }

    // ---- epilogue: C/D layout col=lane&15 (pixel), row=kq*4+reg (o) ----
    #pragma unroll
    for (int mt = 0; mt < 4; ++mt) {
        const f32x4 bv = *(const f32x4*)(bias + mt * 16 + kq * 4);
        #pragma unroll
        for (int r = 0; r < 4; ++r) {
            const int o = mt * 16 + kq * 4 + r;
            out[((b * 64 + o) * 128 + h) * 128 + wpix] = acc[mt][r] + bv[r];
        }
    }
}

extern "C" void kernel_launch(void* const* d_in, const int* in_sizes, int n_in,
                              void* d_out, int out_size, void* d_ws, size_t ws_size,
                              hipStream_t stream)
{
    const float* input  = (const float*)d_in[0];
    // d_in[1] = depth, unused by the reference
    const float* offset = (const float*)d_in[2];
    const float* mask   = (const float*)d_in[3];
    const float* weight = (const float*)d_in[4];
    const float* bias   = (const float*)d_in[5];
    float* out = (float*)d_out;

    unsigned short* nhwc = (unsigned short*)d_ws;                    // 8.39 MB
    unsigned short* wT2  = nhwc + (size_t)4 * HW * CC;               // 73728 B
    int* flag = (int*)((char*)d_ws + (16u << 20));                   // 16 MB offset

    hipMemsetAsync(flag, 0, 4, stream);
    ddc_fused16<<<dim3(256), dim3(1024), 0, stream>>>(
        input, nhwc, weight, wT2, offset, mask, bias, out, flag);
}

// Round 9
// 110.748 us; speedup vs baseline: 1.3420x; 1.3420x over previous
//
#include <hip/hip_runtime.h>

// DepthDeformConv — round 17: inline NCHW->NHWC transpose in main.
//   r16 fusion failed (spin-sync cache invalidation -> 148us): REVERTED.
//   Its counters finally showed main: VGPR 52, VALUBusy 17.6, MfmaUtil 2.2,
//   conflicts ~4% -> no dominant pipe; ~44us = VALU ~8 + LDS ~11 + VMEM ~10
//   poorly overlapped. Rebalancing conserves work -> always 44-46 (r8-r15).
//   Only work/round REMOVAL ever won. This round removes the 2048-block
//   transpose dispatch + 25MB nhwc round-trip: main stages fp32 rows
//   coalesced, converts (v_cvt_pk_bf16_f32, RNE bit-identical), transposes
//   via a 16.5KB LDS scratch union-aliased with sten, writes the swizzled
//   window directly. Fallback reads fp32 NCHW + cvt (same bf16 values).
//   Prep shrinks to an 18-block weight repack. T5 setprio around MFMAs.
//   LDS 155KB. nhwc workspace kept ONLY for fallback? No - fallback is
//   fp32-direct, nhwc fully gone.

typedef __attribute__((ext_vector_type(8))) short bf16x8;
typedef __attribute__((ext_vector_type(4))) float f32x4;
typedef __attribute__((ext_vector_type(2))) float f32x2;
typedef __attribute__((ext_vector_type(2))) unsigned int u32x2;
typedef __attribute__((ext_vector_type(4))) unsigned int u32x4;

#define HH 128
#define WW 128
#define CC 64
#define OO 64
#define HW (128 * 128)

__device__ __forceinline__ unsigned f32_to_bf16_rne(float f) {
    unsigned u = __float_as_uint(f);
    return (u + 0x7FFFu + ((u >> 16) & 1u)) >> 16;
}

__device__ __forceinline__ unsigned cvtpk_bf16(float lo, float hi) {
    unsigned r;
    asm("v_cvt_pk_bf16_f32 %0, %1, %2" : "=v"(r) : "v"(lo), "v"(hi));
    return r;
}

// ---------------- kernel 1: weight repack only (18 blocks) ----------------
__global__ __launch_bounds__(256)
void prep_w17(const float* __restrict__ weight,
              unsigned short* __restrict__ wT2)
{
    const int d  = blockIdx.x * 256 + threadIdx.x;  // 0..4607
    const int o  = d & 63;
    const int k8 = d >> 6;                          // 0..71
    const int kt = k8 >> 3;
    const int c8 = k8 & 7;
    u32x4 pk;
    #pragma unroll
    for (int jj = 0; jj < 4; ++jj) {
        unsigned lo = f32_to_bf16_rne(weight[o * 576 + (c8 * 8 + 2 * jj)     * 9 + kt]);
        unsigned hi = f32_to_bf16_rne(weight[o * 576 + (c8 * 8 + 2 * jj + 1) * 9 + kt]);
        pk[jj] = lo | (hi << 16);
    }
    *(u32x4*)(wT2 + (size_t)d * 8) = pk;
}

// ---------------- kernel 2: fused transpose-stage + sample + MFMA ----------------
__global__ __launch_bounds__(1024)
void ddc_inline17(const float* __restrict__ input,
                  const unsigned short* __restrict__ wT2,
                  const float* __restrict__ offset,
                  const float* __restrict__ mask,
                  const float* __restrict__ bias,
                  float* __restrict__ out)
{
    // 8-row bf16 NHWC window, chunk-swizzled: win u32x4 index
    //   idx(slot,x,c8pos) = slot*1024 + x*8 + c8pos, holding channel chunk
    //   c8pos ^ (x&7). Reader at chunk ch uses pos = ch ^ (x&7).
    __shared__ u32x4 win[8192];            // 128 KB
    __shared__ unsigned scratch[6912];     // 27 KB: tileN (phase A) / sten (taps)

    const int blk0 = blockIdx.x;           // 256 = 4b * 64 h-pairs
    const int blk  = (blk0 & 7) * 32 + (blk0 >> 3);   // XCD-chunked swizzle
    const int b    = blk >> 6;
    const int h0   = (blk & 63) * 2;
    const int ys   = h0 - 3;               // window start row
    const int tid  = threadIdx.x;
    const int wave = tid >> 6;             // 16 waves
    const int lane = tid & 63;
    const int l15  = lane & 15;
    const int kq   = lane >> 4;
    const int hr   = wave >> 3;            // waves 0-7 -> h0, 8-15 -> h0+1
    const int h    = h0 + hr;
    const int wpix = (wave & 7) * 16 + l15;

    const float* ib = input + (size_t)b * 64 * HW;

    // ================= phase A: stage window with inline transpose =================
    // per slot: fp32 row (64c x 128x) -> bf16 NCHW tile -> swizzled NHWC win slot
    unsigned (*tileN)[66] = (unsigned (*)[66])scratch;    // 64 x 66 u32 = 16.5 KB
    #pragma unroll 1
    for (int slot = 0; slot < 8; ++slot) {
        const int y = ys + slot;
        const bool yok = (y >= 0) & (y < HH);
        if (yok) {
            #pragma unroll
            for (int it = 0; it < 2; ++it) {
                const int f  = it * 1024 + tid;           // 0..2047
                const int c  = f >> 5, x4 = f & 31;
                const f32x4 v = *(const f32x4*)(ib + ((size_t)c * 128 + y) * 128 + x4 * 4);
                u32x2 w;
                w[0] = cvtpk_bf16(v[0], v[1]);
                w[1] = cvtpk_bf16(v[2], v[3]);
                *(u32x2*)&tileN[c][x4 * 2] = w;
            }
        }
        __syncthreads();
        if (yok) {
            const int x  = tid >> 3;                      // 0..127
            const int c8 = tid & 7;
            const int xw = x >> 1, sh = (x & 1) * 16;
            u32x4 pk;
            #pragma unroll
            for (int j = 0; j < 4; ++j) {
                const unsigned lo = (tileN[c8 * 8 + 2 * j    ][xw] >> sh) & 0xFFFFu;
                const unsigned hi = (tileN[c8 * 8 + 2 * j + 1][xw] >> sh) & 0xFFFFu;
                pk[j] = lo | (hi << 16);
            }
            win[slot * 1024 + x * 8 + (c8 ^ (x & 7))] = pk;
        }
        __syncthreads();
    }

    // ---- stage offset/mask planes into scratch (tileN now dead) ----
    float* sten = (float*)scratch;
    #pragma unroll
    for (int it = 0; it < 7; ++it) {
        const int f = it * 1024 + tid;                // 0..7167
        if (f < 6912) {
            const int plane = f >> 8;                 // 0..26
            const int fr    = (f >> 7) & 1;
            const int x     = f & 127;
            sten[f] = (plane < 18)
                ? offset[((b * 18 + plane)      * 128 + (h0 + fr)) * 128 + x]
                : mask  [((b * 9 + (plane - 18))* 128 + (h0 + fr)) * 128 + x];
        }
    }
    __syncthreads();

    // ================= phase B: taps (r15 body; fallback reads fp32) ===============
    f32x4 acc[4];
    #pragma unroll
    for (int mt = 0; mt < 4; ++mt) acc[mt] = (f32x4){0.f, 0.f, 0.f, 0.f};

    const u32x4* wsrc = (const u32x4*)wT2;

    #pragma unroll
    for (int kt = 0; kt < 9; ++kt) {
        const float oy = sten[(2 * kt)     * 256 + hr * 128 + wpix];
        const float ox = sten[(2 * kt + 1) * 256 + hr * 128 + wpix];
        const float m  = sten[(18 + kt)    * 256 + hr * 128 + wpix];

        const float py = (float)(h - 1 + kt / 3) + oy;
        const float px = (float)(wpix - 1 + kt % 3) + ox;
        const float y0f = floorf(py), x0f = floorf(px);
        const int y0 = (int)y0f, x0 = (int)x0f;
        const float wy = py - y0f, wx = px - x0f;
        const int y1 = y0 + 1, x1 = x0 + 1;
        const bool vy0 = (y0 >= 0) & (y0 < HH);
        const bool vy1 = (y1 >= 0) & (y1 < HH);
        const bool vx0 = (x0 >= 0) & (x0 < WW);
        const bool vx1 = (x1 >= 0) & (x1 < WW);
        const int y0c = min(max(y0, 0), HH - 1), y1c = min(max(y1, 0), HH - 1);
        const int x0c = min(max(x0, 0), WW - 1), x1c = min(max(x1, 0), WW - 1);
        const float wy1 = 1.f - wy, wx1 = 1.f - wx;
        const float c00 = (vy0 && vx0) ? wy1 * wx1 * m : 0.f;
        const float c01 = (vy0 && vx1) ? wy1 * wx  * m : 0.f;
        const float c10 = (vy1 && vx0) ? wy  * wx1 * m : 0.f;
        const float c11 = (vy1 && vx1) ? wy  * wx  * m : 0.f;

        const int s0 = y0c - ys, s1 = y1c - ys;
        const bool in0 = ((unsigned)s0 < 8u);
        const bool in1 = ((unsigned)s1 < 8u);
        const int r0 = (in0 ? s0 : 0) * 1024;
        const int r1 = (in1 ? s1 : 0) * 1024;
        const int bx0 = x0c * 8, sx0 = x0c & 7;
        const int bx1 = x1c * 8, sx1 = x1c & 7;

        const f32x2 vc00 = (f32x2){c00, c00}, vc01 = (f32x2){c01, c01};
        const f32x2 vc10 = (f32x2){c10, c10}, vc11 = (f32x2){c11, c11};

        #pragma unroll
        for (int ks = 0; ks < 2; ++ks) {
            const int ch = ks * 4 + kq;

            u32x4 w00 = win[r0 + bx0 + (ch ^ sx0)];
            u32x4 w01 = win[r0 + bx1 + (ch ^ sx1)];
            u32x4 w10 = win[r1 + bx0 + (ch ^ sx0)];
            u32x4 w11 = win[r1 + bx1 + (ch ^ sx1)];
            if (!in0) {                    // rare: |oy| past window -> fp32 direct
                const float* p = ib + (size_t)ch * 8 * HW + (size_t)y0c * WW;
                #pragma unroll
                for (int j = 0; j < 4; ++j) {
                    w00[j] = cvtpk_bf16(p[(2*j)*HW + x0c], p[(2*j+1)*HW + x0c]);
                    w01[j] = cvtpk_bf16(p[(2*j)*HW + x1c], p[(2*j+1)*HW + x1c]);
                }
            }
            if (!in1) {
                const float* p = ib + (size_t)ch * 8 * HW + (size_t)y1c * WW;
                #pragma unroll
                for (int j = 0; j < 4; ++j) {
                    w10[j] = cvtpk_bf16(p[(2*j)*HW + x0c], p[(2*j+1)*HW + x0c]);
                    w11[j] = cvtpk_bf16(p[(2*j)*HW + x1c], p[(2*j+1)*HW + x1c]);
                }
            }

            u32x4 pk;
            #pragma unroll
            for (int j = 0; j < 4; ++j) {
                const f32x2 A = (f32x2){__uint_as_float(w00[j] << 16),
                                        __uint_as_float(w00[j] & 0xFFFF0000u)};
                const f32x2 B = (f32x2){__uint_as_float(w01[j] << 16),
                                        __uint_as_float(w01[j] & 0xFFFF0000u)};
                const f32x2 D = (f32x2){__uint_as_float(w10[j] << 16),
                                        __uint_as_float(w10[j] & 0xFFFF0000u)};
                const f32x2 E = (f32x2){__uint_as_float(w11[j] << 16),
                                        __uint_as_float(w11[j] & 0xFFFF0000u)};
                const f32x2 S = vc00 * A + vc01 * B + vc10 * D + vc11 * E;
                pk[j] = cvtpk_bf16(S[0], S[1]);
            }
            const bf16x8 bfrag = __builtin_bit_cast(bf16x8, pk);

            const u32x4* wp = wsrc + (kt * 8 + ks * 4 + kq) * 64 + l15;
            __builtin_amdgcn_s_setprio(1);
            acc[0] = __builtin_amdgcn_mfma_f32_16x16x32_bf16(
                __builtin_bit_cast(bf16x8, wp[0]),  bfrag, acc[0], 0, 0, 0);
            acc[1] = __builtin_amdgcn_mfma_f32_16x16x32_bf16(
                __builtin_bit_cast(bf16x8, wp[16]), bfrag, acc[1], 0, 0, 0);
            acc[2] = __builtin_amdgcn_mfma_f32_16x16x32_bf16(
                __builtin_bit_cast(bf16x8, wp[32]), bfrag, acc[2], 0, 0, 0);
            acc[3] = __builtin_amdgcn_mfma_f32_16x16x32_bf16(
                __builtin_bit_cast(bf16x8, wp[48]), bfrag, acc[3], 0, 0, 0);
            __builtin_amdgcn_s_setprio(0);
        }
    }

    // ---- epilogue: C/D layout col=lane&15 (pixel), row=kq*4+reg (o) ----
    #pragma unroll
    for (int mt = 0; mt < 4; ++mt) {
        const f32x4 bv = *(const f32x4*)(bias + mt * 16 + kq * 4);
        #pragma unroll
        for (int r = 0; r < 4; ++r) {
            const int o = mt * 16 + kq * 4 + r;
            out[((b * 64 + o) * 128 + h) * 128 + wpix] = acc[mt][r] + bv[r];
        }
    }
}

extern "C" void kernel_launch(void* const* d_in, const int* in_sizes, int n_in,
                              void* d_out, int out_size, void* d_ws, size_t ws_size,
                              hipStream_t stream)
{
    const float* input  = (const float*)d_in[0];
    // d_in[1] = depth, unused by the reference
    const float* offset = (const float*)d_in[2];
    const float* mask   = (const float*)d_in[3];
    const float* weight = (const float*)d_in[4];
    const float* bias   = (const float*)d_in[5];
    float* out = (float*)d_out;

    unsigned short* wT2 = (unsigned short*)d_ws;                     // 73728 B

    prep_w17<<<dim3(18), dim3(256), 0, stream>>>(weight, wT2);
    ddc_inline17<<<dim3(256), dim3(1024), 0, stream>>>(
        input, wT2, offset, mask, bias, out);
}

// Round 10
// 107.965 us; speedup vs baseline: 1.3766x; 1.0258x over previous
//
#include <hip/hip_runtime.h>

// DepthDeformConv — round 18: r15 base + issue-order surgery.
//   r17 (inline transpose) regressed 104.6->110.7: in-kernel transpose
//   barriers + fp32 staging bytes cost more than the prep dispatch saved.
//   REVERT to r15. Remaining exposed latency found by arithmetic: the
//   out-of-window fallback fires on ~40% of wave-taps (1-(1-0.008)^64),
//   and r15 issues those divergent global gathers AFTER the LDS corner
//   reads, consumed ~10 instrs later -> ~500cy exposed, 7x per wave.
//   Changes (numerics identical): (1) weight loads hoisted to tap top
//   (depend only on kt) -> 8 VMEM in flight under stencil math; (2)
//   fallback as if/else phi: globals issue FIRST, LDS reads in the else
//   (exec-masked to in-window lanes, no clamp needed, no cndmask);
//   (3) T5 setprio around MFMA clusters (desynced waves = its regime).

typedef __attribute__((ext_vector_type(8))) short bf16x8;
typedef __attribute__((ext_vector_type(4))) float f32x4;
typedef __attribute__((ext_vector_type(2))) float f32x2;
typedef __attribute__((ext_vector_type(4))) unsigned int u32x4;

#define HH 128
#define WW 128
#define CC 64
#define OO 64
#define HW (128 * 128)

__device__ __forceinline__ unsigned f32_to_bf16_rne(float f) {
    unsigned u = __float_as_uint(f);
    return (u + 0x7FFFu + ((u >> 16) & 1u)) >> 16;
}

__device__ __forceinline__ unsigned cvtpk_bf16(float lo, float hi) {
    unsigned r;
    asm("v_cvt_pk_bf16_f32 %0, %1, %2" : "=v"(r) : "v"(lo), "v"(hi));
    return r;
}

// ---------------- kernel 1: fused NCHW->NHWC bf16 + weight repack ----------------
__global__ __launch_bounds__(256)
void prep_fused18(const float* __restrict__ input,
                  unsigned short* __restrict__ nhwc,
                  const float* __restrict__ weight,
                  unsigned short* __restrict__ wT2)
{
    __shared__ unsigned tile[64][33];
    const int tid = threadIdx.x;
    const int blk = blockIdx.x;

    if (blk >= 2048) {
        // weight repack: wT2[(kt*8 + c8)*64 + o] = bf16 w for ch c8*8..+7, tap kt
        const int d  = (blk - 2048) * 256 + tid;    // 0..4607
        const int o  = d & 63;
        const int k8 = d >> 6;                      // 0..71
        const int kt = k8 >> 3;
        const int c8 = k8 & 7;
        u32x4 pk;
        #pragma unroll
        for (int jj = 0; jj < 4; ++jj) {
            unsigned lo = f32_to_bf16_rne(weight[o * 576 + (c8 * 8 + 2 * jj)     * 9 + kt]);
            unsigned hi = f32_to_bf16_rne(weight[o * 576 + (c8 * 8 + 2 * jj + 1) * 9 + kt]);
            pk[jj] = lo | (hi << 16);
        }
        *(u32x4*)(wT2 + (size_t)d * 8) = pk;
        return;
    }

    const int b  = blk >> 9;
    const int y  = (blk >> 2) & 127;
    const int xbase = (blk & 3) * 32;
    #pragma unroll
    for (int it = 0; it < 2; ++it) {
        int flat = it * 256 + tid;          // 0..511
        int c = flat >> 3, x4 = flat & 7;   // 64c x 8 float4-groups
        const f32x4 v = *(const f32x4*)(input + ((b * 64 + c) * 128 + y) * 128 + xbase + x4 * 4);
        tile[c][x4 * 4 + 0] = f32_to_bf16_rne(v[0]);
        tile[c][x4 * 4 + 1] = f32_to_bf16_rne(v[1]);
        tile[c][x4 * 4 + 2] = f32_to_bf16_rne(v[2]);
        tile[c][x4 * 4 + 3] = f32_to_bf16_rne(v[3]);
    }
    __syncthreads();
    {
        int x = tid >> 3, cg = tid & 7;     // 32x * 8 channel-groups
        unsigned r0 = tile[cg * 8 + 0][x], r1 = tile[cg * 8 + 1][x];
        unsigned r2 = tile[cg * 8 + 2][x], r3 = tile[cg * 8 + 3][x];
        unsigned r4 = tile[cg * 8 + 4][x], r5 = tile[cg * 8 + 5][x];
        unsigned r6 = tile[cg * 8 + 6][x], r7 = tile[cg * 8 + 7][x];
        u32x4 pk;
        pk[0] = r0 | (r1 << 16); pk[1] = r2 | (r3 << 16);
        pk[2] = r4 | (r5 << 16); pk[3] = r6 | (r7 << 16);
        *(u32x4*)(nhwc + ((size_t)((b * 128 + y) * 128 + xbase + x)) * 64 + cg * 8) = pk;
    }
}

// ---------------- kernel 2: fused sample + MFMA, issue-ordered taps ----------------
__global__ __launch_bounds__(1024)
void ddc_order18(const unsigned short* __restrict__ nhwc,
                 const unsigned short* __restrict__ wT2,
                 const float* __restrict__ offset,
                 const float* __restrict__ mask,
                 const float* __restrict__ bias,
                 float* __restrict__ out)
{
    // 8-row bf16 NHWC window, chunk-swizzled: LDS u32x4 index
    //   idx(slot,x,c8pos) = slot*1024 + x*8 + c8pos, holding source chunk
    //   c8pos ^ (x&7). Reader at chunk ch uses pos = ch ^ (x&7).
    __shared__ u32x4 win[8192];            // 128 KB
    __shared__ float sten[6912];           // 27 KB: [plane 0..26][hr 0..1][x 0..127]

    const int blk0 = blockIdx.x;           // 256 = 4b * 64 h-pairs
    const int blk  = (blk0 & 7) * 32 + (blk0 >> 3);   // XCD-chunked swizzle
    const int b    = blk >> 6;
    const int h0   = (blk & 63) * 2;
    const int ys   = h0 - 3;               // window start row
    const int tid  = threadIdx.x;
    const int wave = tid >> 6;             // 16 waves
    const int lane = tid & 63;
    const int l15  = lane & 15;
    const int kq   = lane >> 4;
    const int hr   = wave >> 3;            // waves 0-7 -> h0, 8-15 -> h0+1
    const int h    = h0 + hr;
    const int wpix = (wave & 7) * 16 + l15;

    f32x4 acc[4];
    #pragma unroll
    for (int mt = 0; mt < 4; ++mt) acc[mt] = (f32x4){0.f, 0.f, 0.f, 0.f};

    const unsigned short* nb = nhwc + (size_t)b * HW * CC;
    const u32x4* wsrc = (const u32x4*)wT2;

    // ---- stage offset/mask planes for both rows (27 planes x 2 x 128) ----
    #pragma unroll
    for (int it = 0; it < 7; ++it) {
        const int f = it * 1024 + tid;                // 0..7167
        if (f < 6912) {
            const int plane = f >> 8;                 // 0..26
            const int fr    = (f >> 7) & 1;
            const int x     = f & 127;
            sten[f] = (plane < 18)
                ? offset[((b * 18 + plane)      * 128 + (h0 + fr)) * 128 + x]
                : mask  [((b * 9 + (plane - 18))* 128 + (h0 + fr)) * 128 + x];
        }
    }

    // ---- stage window rows ys..ys+7 (swizzled source, linear LDS dest) ----
    #pragma unroll
    for (int slot = 0; slot < 8; ++slot) {
        const int y = ys + slot;
        if (y >= 0 && y < HH) {
            const int q  = tid;                       // 0..1023 = one full row
            const int x  = q >> 3;
            const int c8 = q & 7;
            win[slot * 1024 + q] =
                *(const u32x4*)(nb + ((size_t)(y * WW + x)) * CC + ((c8 ^ (x & 7)) << 3));
        }
    }
    __syncthreads();                                  // the ONLY barrier

    // ---- K loop: fully unrolled, barrier-free, issue-ordered ----
    #pragma unroll
    for (int kt = 0; kt < 9; ++kt) {
        // (1) weight loads FIRST (depend only on kt; L2-resident, 8 VMEM)
        const u32x4* wpa = wsrc + (kt * 8 + kq)     * 64 + l15;   // ks=0
        const u32x4* wpb = wsrc + (kt * 8 + 4 + kq) * 64 + l15;   // ks=1
        const u32x4 wa0 = wpa[0], wa1 = wpa[16], wa2 = wpa[32], wa3 = wpa[48];
        const u32x4 wb0 = wpb[0], wb1 = wpb[16], wb2 = wpb[32], wb3 = wpb[48];

        // (2) stencil scalars from LDS (16-lane broadcast, conflict-free)
        const float oy = sten[(2 * kt)     * 256 + hr * 128 + wpix];
        const float ox = sten[(2 * kt + 1) * 256 + hr * 128 + wpix];
        const float m  = sten[(18 + kt)    * 256 + hr * 128 + wpix];

        // (3) stencil math
        const float py = (float)(h - 1 + kt / 3) + oy;
        const float px = (float)(wpix - 1 + kt % 3) + ox;
        const float y0f = floorf(py), x0f = floorf(px);
        const int y0 = (int)y0f, x0 = (int)x0f;
        const float wy = py - y0f, wx = px - x0f;
        const int y1 = y0 + 1, x1 = x0 + 1;
        const bool vy0 = (y0 >= 0) & (y0 < HH);
        const bool vy1 = (y1 >= 0) & (y1 < HH);
        const bool vx0 = (x0 >= 0) & (x0 < WW);
        const bool vx1 = (x1 >= 0) & (x1 < WW);
        const int y0c = min(max(y0, 0), HH - 1), y1c = min(max(y1, 0), HH - 1);
        const int x0c = min(max(x0, 0), WW - 1), x1c = min(max(x1, 0), WW - 1);
        const float wy1 = 1.f - wy, wx1 = 1.f - wx;
        const float c00 = (vy0 && vx0) ? wy1 * wx1 * m : 0.f;
        const float c01 = (vy0 && vx1) ? wy1 * wx  * m : 0.f;
        const float c10 = (vy1 && vx0) ? wy  * wx1 * m : 0.f;
        const float c11 = (vy1 && vx1) ? wy  * wx  * m : 0.f;

        const int s0 = y0c - ys, s1 = y1c - ys;
        const bool in0 = ((unsigned)s0 < 8u);
        const bool in1 = ((unsigned)s1 < 8u);
        const int bx0 = x0c * 8, sx0 = x0c & 7;
        const int bx1 = x1c * 8, sx1 = x1c & 7;

        // (4) corners: fallback globals issue FIRST (if-branch), in-window
        //     lanes read LDS in the else (exec-masked -> no clamp needed)
        u32x4 w00a, w01a, w00b, w01b;
        if (!in0) {                        // ~40% of wave-taps, <1% of lanes
            const unsigned short* p0 = nb + ((size_t)y0c * WW + x0c) * CC;
            const unsigned short* p1 = nb + ((size_t)y0c * WW + x1c) * CC;
            w00a = *(const u32x4*)(p0 + kq * 8);
            w01a = *(const u32x4*)(p1 + kq * 8);
            w00b = *(const u32x4*)(p0 + 32 + kq * 8);
            w01b = *(const u32x4*)(p1 + 32 + kq * 8);
        } else {
            const int r0 = s0 * 1024;
            w00a = win[r0 + bx0 + (kq ^ sx0)];
            w01a = win[r0 + bx1 + (kq ^ sx1)];
            w00b = win[r0 + bx0 + ((4 + kq) ^ sx0)];
            w01b = win[r0 + bx1 + ((4 + kq) ^ sx1)];
        }
        u32x4 w10a, w11a, w10b, w11b;
        if (!in1) {
            const unsigned short* p0 = nb + ((size_t)y1c * WW + x0c) * CC;
            const unsigned short* p1 = nb + ((size_t)y1c * WW + x1c) * CC;
            w10a = *(const u32x4*)(p0 + kq * 8);
            w11a = *(const u32x4*)(p1 + kq * 8);
            w10b = *(const u32x4*)(p0 + 32 + kq * 8);
            w11b = *(const u32x4*)(p1 + 32 + kq * 8);
        } else {
            const int r1 = s1 * 1024;
            w10a = win[r1 + bx0 + (kq ^ sx0)];
            w11a = win[r1 + bx1 + (kq ^ sx1)];
            w10b = win[r1 + bx0 + ((4 + kq) ^ sx0)];
            w11b = win[r1 + bx1 + ((4 + kq) ^ sx1)];
        }

        const f32x2 vc00 = (f32x2){c00, c00}, vc01 = (f32x2){c01, c01};
        const f32x2 vc10 = (f32x2){c10, c10}, vc11 = (f32x2){c11, c11};

        // (5) blend + pack + MFMA, ks = 0 then 1
        #pragma unroll
        for (int ks = 0; ks < 2; ++ks) {
            const u32x4 w00 = ks ? w00b : w00a;
            const u32x4 w01 = ks ? w01b : w01a;
            const u32x4 w10 = ks ? w10b : w10a;
            const u32x4 w11 = ks ? w11b : w11a;
            u32x4 pk;
            #pragma unroll
            for (int j = 0; j < 4; ++j) {
                const f32x2 A = (f32x2){__uint_as_float(w00[j] << 16),
                                        __uint_as_float(w00[j] & 0xFFFF0000u)};
                const f32x2 B = (f32x2){__uint_as_float(w01[j] << 16),
                                        __uint_as_float(w01[j] & 0xFFFF0000u)};
                const f32x2 D = (f32x2){__uint_as_float(w10[j] << 16),
                                        __uint_as_float(w10[j] & 0xFFFF0000u)};
                const f32x2 E = (f32x2){__uint_as_float(w11[j] << 16),
                                        __uint_as_float(w11[j] & 0xFFFF0000u)};
                const f32x2 S = vc00 * A + vc01 * B + vc10 * D + vc11 * E;
                pk[j] = cvtpk_bf16(S[0], S[1]);
            }
            const bf16x8 bfrag = __builtin_bit_cast(bf16x8, pk);

            __builtin_amdgcn_s_setprio(1);
            acc[0] = __builtin_amdgcn_mfma_f32_16x16x32_bf16(
                __builtin_bit_cast(bf16x8, ks ? wb0 : wa0), bfrag, acc[0], 0, 0, 0);
            acc[1] = __builtin_amdgcn_mfma_f32_16x16x32_bf16(
                __builtin_bit_cast(bf16x8, ks ? wb1 : wa1), bfrag, acc[1], 0, 0, 0);
            acc[2] = __builtin_amdgcn_mfma_f32_16x16x32_bf16(
                __builtin_bit_cast(bf16x8, ks ? wb2 : wa2), bfrag, acc[2], 0, 0, 0);
            acc[3] = __builtin_amdgcn_mfma_f32_16x16x32_bf16(
                __builtin_bit_cast(bf16x8, ks ? wb3 : wa3), bfrag, acc[3], 0, 0, 0);
            __builtin_amdgcn_s_setprio(0);
        }
    }

    // ---- epilogue: C/D layout col=lane&15 (pixel), row=kq*4+reg (o) ----
    #pragma unroll
    for (int mt = 0; mt < 4; ++mt) {
        const f32x4 bv = *(const f32x4*)(bias + mt * 16 + kq * 4);
        #pragma unroll
        for (int r = 0; r < 4; ++r) {
            const int o = mt * 16 + kq * 4 + r;
            out[((b * 64 + o) * 128 + h) * 128 + wpix] = acc[mt][r] + bv[r];
        }
    }
}

extern "C" void kernel_launch(void* const* d_in, const int* in_sizes, int n_in,
                              void* d_out, int out_size, void* d_ws, size_t ws_size,
                              hipStream_t stream)
{
    const float* input  = (const float*)d_in[0];
    // d_in[1] = depth, unused by the reference
    const float* offset = (const float*)d_in[2];
    const float* mask   = (const float*)d_in[3];
    const float* weight = (const float*)d_in[4];
    const float* bias   = (const float*)d_in[5];
    float* out = (float*)d_out;

    unsigned short* nhwc = (unsigned short*)d_ws;                    // 8.39 MB
    unsigned short* wT2  = nhwc + (size_t)4 * HW * CC;               // 73728 B

    prep_fused18<<<dim3(2066), dim3(256), 0, stream>>>(input, nhwc, weight, wT2);
    ddc_order18<<<dim3(256), dim3(1024), 0, stream>>>(nhwc, wT2, offset, mask, bias, out);
}

// Round 11
// 106.479 us; speedup vs baseline: 1.3958x; 1.0140x over previous
//
#include <hip/hip_runtime.h>

// DepthDeformConv — round 19: fence-pinned cross-tap pipeline, 256-VGPR shape.
//   Model fitting all 10 rounds: compiler allocates ~52 VGPR regardless of
//   cap -> every tap is ~16 serialized issue->wait->consume load chains of
//   ~500cy = ~40us/wave, invariant to waves/source/barriers (all observed).
//   r13 tried pipelining but hipcc sinks loads to uses (rule #18) without
//   fences. This round: 512thr/8-wave/1-row blocks (VGPR cap 256, no spill
//   risk), 27 stencil scalars prefetched to registers (r10, kills sten LDS
//   reads), and a fully-unrolled 9-tap loop where prepare(t+1) {stencil
//   VALU + issue 8 corner ds_read + 8 weight loads into buf[(t+1)&1],
//   fallback globals under exec mask} is PINNED before consume(t) {blend +
//   8 MFMA on buf[t&1]} with __builtin_amdgcn_sched_barrier(0) fences.
//   Counted lgkm/vm waits let t's results be consumed while t+1 is in
//   flight. Waits/tap ~16 -> ~2. Numerics identical to r15 (same blend,
//   same tap order) -> absmax unchanged.

typedef __attribute__((ext_vector_type(8))) short bf16x8;
typedef __attribute__((ext_vector_type(4))) float f32x4;
typedef __attribute__((ext_vector_type(2))) float f32x2;
typedef __attribute__((ext_vector_type(4))) unsigned int u32x4;

#define HH 128
#define WW 128
#define CC 64
#define OO 64
#define HW (128 * 128)

__device__ __forceinline__ unsigned f32_to_bf16_rne(float f) {
    unsigned u = __float_as_uint(f);
    return (u + 0x7FFFu + ((u >> 16) & 1u)) >> 16;
}

__device__ __forceinline__ unsigned cvtpk_bf16(float lo, float hi) {
    unsigned r;
    asm("v_cvt_pk_bf16_f32 %0, %1, %2" : "=v"(r) : "v"(lo), "v"(hi));
    return r;
}

// ---------------- kernel 1: fused NCHW->NHWC bf16 + weight repack ----------------
__global__ __launch_bounds__(256)
void prep_fused19(const float* __restrict__ input,
                  unsigned short* __restrict__ nhwc,
                  const float* __restrict__ weight,
                  unsigned short* __restrict__ wT2)
{
    __shared__ unsigned tile[64][33];
    const int tid = threadIdx.x;
    const int blk = blockIdx.x;

    if (blk >= 2048) {
        const int d  = (blk - 2048) * 256 + tid;    // 0..4607
        const int o  = d & 63;
        const int k8 = d >> 6;                      // 0..71
        const int kt = k8 >> 3;
        const int c8 = k8 & 7;
        u32x4 pk;
        #pragma unroll
        for (int jj = 0; jj < 4; ++jj) {
            unsigned lo = f32_to_bf16_rne(weight[o * 576 + (c8 * 8 + 2 * jj)     * 9 + kt]);
            unsigned hi = f32_to_bf16_rne(weight[o * 576 + (c8 * 8 + 2 * jj + 1) * 9 + kt]);
            pk[jj] = lo | (hi << 16);
        }
        *(u32x4*)(wT2 + (size_t)d * 8) = pk;
        return;
    }

    const int b  = blk >> 9;
    const int y  = (blk >> 2) & 127;
    const int xbase = (blk & 3) * 32;
    #pragma unroll
    for (int it = 0; it < 2; ++it) {
        int flat = it * 256 + tid;          // 0..511
        int c = flat >> 3, x4 = flat & 7;   // 64c x 8 float4-groups
        const f32x4 v = *(const f32x4*)(input + ((b * 64 + c) * 128 + y) * 128 + xbase + x4 * 4);
        tile[c][x4 * 4 + 0] = f32_to_bf16_rne(v[0]);
        tile[c][x4 * 4 + 1] = f32_to_bf16_rne(v[1]);
        tile[c][x4 * 4 + 2] = f32_to_bf16_rne(v[2]);
        tile[c][x4 * 4 + 3] = f32_to_bf16_rne(v[3]);
    }
    __syncthreads();
    {
        int x = tid >> 3, cg = tid & 7;     // 32x * 8 channel-groups
        unsigned r0 = tile[cg * 8 + 0][x], r1 = tile[cg * 8 + 1][x];
        unsigned r2 = tile[cg * 8 + 2][x], r3 = tile[cg * 8 + 3][x];
        unsigned r4 = tile[cg * 8 + 4][x], r5 = tile[cg * 8 + 5][x];
        unsigned r6 = tile[cg * 8 + 6][x], r7 = tile[cg * 8 + 7][x];
        u32x4 pk;
        pk[0] = r0 | (r1 << 16); pk[1] = r2 | (r3 << 16);
        pk[2] = r4 | (r5 << 16); pk[3] = r6 | (r7 << 16);
        *(u32x4*)(nhwc + ((size_t)((b * 128 + y) * 128 + xbase + x)) * 64 + cg * 8) = pk;
    }
}

// ---------------- kernel 2: fence-pinned pipelined sample + MFMA ----------------
__global__ __launch_bounds__(512, 2)
void ddc_pipe19(const unsigned short* __restrict__ nhwc,
                const unsigned short* __restrict__ wT2,
                const float* __restrict__ offset,
                const float* __restrict__ mask,
                const float* __restrict__ bias,
                float* __restrict__ out)
{
    // 8-row bf16 NHWC window, chunk-swizzled (see r9): only LDS in kernel.
    __shared__ u32x4 win[8192];            // 128 KB

    const int blk0 = blockIdx.x;           // 512 = 4b * 128h
    const int blk  = (blk0 & 7) * 64 + (blk0 >> 3);   // XCD-chunked swizzle
    const int b    = blk >> 7;
    const int h    = blk & 127;
    const int ys   = h - 3;
    const int tid  = threadIdx.x;
    const int wave = tid >> 6;             // 8 pixel groups
    const int lane = tid & 63;
    const int l15  = lane & 15;
    const int kq   = lane >> 4;
    const int wpix = wave * 16 + l15;

    f32x4 acc[4];
    #pragma unroll
    for (int mt = 0; mt < 4; ++mt) acc[mt] = (f32x4){0.f, 0.f, 0.f, 0.f};

    const unsigned short* nb = nhwc + (size_t)b * HW * CC;
    const u32x4* wsrc = (const u32x4*)wT2;

    // ---- prefetch all per-pixel stencil scalars (27 coalesced loads) ----
    float oyv[9], oxv[9], mv[9];
    #pragma unroll
    for (int kt = 0; kt < 9; ++kt) {
        oyv[kt] = offset[((b * 18 + 2 * kt)     * 128 + h) * 128 + wpix];
        oxv[kt] = offset[((b * 18 + 2 * kt + 1) * 128 + h) * 128 + wpix];
        mv[kt]  = mask  [((b * 9  + kt)         * 128 + h) * 128 + wpix];
    }

    // ---- stage window rows h-3..h+4 (swizzled source, linear LDS dest) ----
    #pragma unroll
    for (int i = 0; i < 16; ++i) {
        const int slot = i >> 1;
        const int y = ys + slot;
        if (y >= 0 && y < HH) {
            const int q  = ((i & 1) << 9) + tid;      // 0..1023 within row
            const int x  = q >> 3;
            const int c8 = q & 7;
            win[slot * 1024 + q] =
                *(const u32x4*)(nb + ((size_t)(y * WW + x)) * CC + ((c8 ^ (x & 7)) << 3));
        }
    }
    __syncthreads();                                  // the ONLY barrier

    // ---- pipeline buffers: [slot][0..3]=ks0 {00,01,10,11}, [4..7]=ks1 ----
    u32x4 cb[2][8];
    u32x4 wb[2][8];
    float pc[2][4];                                   // c00,c01,c10,c11

    // prepare(kt, sl): stencil math (registers only) + issue all 16 loads
    auto prepare = [&](int kt, int sl) {
        const float oy = oyv[kt], ox = oxv[kt], m = mv[kt];
        const float py = (float)(h - 1 + kt / 3) + oy;
        const float px = (float)(wpix - 1 + kt % 3) + ox;
        const float y0f = floorf(py), x0f = floorf(px);
        const int y0 = (int)y0f, x0 = (int)x0f;
        const float wy = py - y0f, wx = px - x0f;
        const int y1 = y0 + 1, x1 = x0 + 1;
        const bool vy0 = (y0 >= 0) & (y0 < HH);
        const bool vy1 = (y1 >= 0) & (y1 < HH);
        const bool vx0 = (x0 >= 0) & (x0 < WW);
        const bool vx1 = (x1 >= 0) & (x1 < WW);
        const int y0c = min(max(y0, 0), HH - 1), y1c = min(max(y1, 0), HH - 1);
        const int x0c = min(max(x0, 0), WW - 1), x1c = min(max(x1, 0), WW - 1);
        const float wy1 = 1.f - wy, wx1 = 1.f - wx;
        pc[sl][0] = (vy0 && vx0) ? wy1 * wx1 * m : 0.f;
        pc[sl][1] = (vy0 && vx1) ? wy1 * wx  * m : 0.f;
        pc[sl][2] = (vy1 && vx0) ? wy  * wx1 * m : 0.f;
        pc[sl][3] = (vy1 && vx1) ? wy  * wx  * m : 0.f;

        const int s0 = y0c - ys, s1 = y1c - ys;
        const bool in0 = ((unsigned)s0 < 8u);
        const bool in1 = ((unsigned)s1 < 8u);
        const int bx0 = x0c * 8, sx0 = x0c & 7;
        const int bx1 = x1c * 8, sx1 = x1c & 7;

        // weights for both ks (8 VMEM, L2-resident, in flight across the fence)
        const u32x4* wpa = wsrc + (kt * 8 + kq)     * 64 + l15;
        const u32x4* wpb = wsrc + (kt * 8 + 4 + kq) * 64 + l15;
        wb[sl][0] = wpa[0];  wb[sl][1] = wpa[16];
        wb[sl][2] = wpa[32]; wb[sl][3] = wpa[48];
        wb[sl][4] = wpb[0];  wb[sl][5] = wpb[16];
        wb[sl][6] = wpb[32]; wb[sl][7] = wpb[48];

        // corners (8 LDS reads, or rare global fallback under exec mask)
        if (!in0) {
            const unsigned short* p0 = nb + ((size_t)y0c * WW + x0c) * CC;
            const unsigned short* p1 = nb + ((size_t)y0c * WW + x1c) * CC;
            cb[sl][0] = *(const u32x4*)(p0 + kq * 8);
            cb[sl][1] = *(const u32x4*)(p1 + kq * 8);
            cb[sl][4] = *(const u32x4*)(p0 + 32 + kq * 8);
            cb[sl][5] = *(const u32x4*)(p1 + 32 + kq * 8);
        } else {
            const int r0 = s0 * 1024;
            cb[sl][0] = win[r0 + bx0 + (kq ^ sx0)];
            cb[sl][1] = win[r0 + bx1 + (kq ^ sx1)];
            cb[sl][4] = win[r0 + bx0 + ((4 + kq) ^ sx0)];
            cb[sl][5] = win[r0 + bx1 + ((4 + kq) ^ sx1)];
        }
        if (!in1) {
            const unsigned short* p0 = nb + ((size_t)y1c * WW + x0c) * CC;
            const unsigned short* p1 = nb + ((size_t)y1c * WW + x1c) * CC;
            cb[sl][2] = *(const u32x4*)(p0 + kq * 8);
            cb[sl][3] = *(const u32x4*)(p1 + kq * 8);
            cb[sl][6] = *(const u32x4*)(p0 + 32 + kq * 8);
            cb[sl][7] = *(const u32x4*)(p1 + 32 + kq * 8);
        } else {
            const int r1 = s1 * 1024;
            cb[sl][2] = win[r1 + bx0 + (kq ^ sx0)];
            cb[sl][3] = win[r1 + bx1 + (kq ^ sx1)];
            cb[sl][6] = win[r1 + bx0 + ((4 + kq) ^ sx0)];
            cb[sl][7] = win[r1 + bx1 + ((4 + kq) ^ sx1)];
        }
    };

    auto consume = [&](int sl) {
        const f32x2 vc00 = (f32x2){pc[sl][0], pc[sl][0]};
        const f32x2 vc01 = (f32x2){pc[sl][1], pc[sl][1]};
        const f32x2 vc10 = (f32x2){pc[sl][2], pc[sl][2]};
        const f32x2 vc11 = (f32x2){pc[sl][3], pc[sl][3]};
        #pragma unroll
        for (int ks = 0; ks < 2; ++ks) {
            const u32x4 w00 = cb[sl][ks * 4 + 0];
            const u32x4 w01 = cb[sl][ks * 4 + 1];
            const u32x4 w10 = cb[sl][ks * 4 + 2];
            const u32x4 w11 = cb[sl][ks * 4 + 3];
            u32x4 pk;
            #pragma unroll
            for (int j = 0; j < 4; ++j) {
                const f32x2 A = (f32x2){__uint_as_float(w00[j] << 16),
                                        __uint_as_float(w00[j] & 0xFFFF0000u)};
                const f32x2 B = (f32x2){__uint_as_float(w01[j] << 16),
                                        __uint_as_float(w01[j] & 0xFFFF0000u)};
                const f32x2 D = (f32x2){__uint_as_float(w10[j] << 16),
                                        __uint_as_float(w10[j] & 0xFFFF0000u)};
                const f32x2 E = (f32x2){__uint_as_float(w11[j] << 16),
                                        __uint_as_float(w11[j] & 0xFFFF0000u)};
                const f32x2 S = vc00 * A + vc01 * B + vc10 * D + vc11 * E;
                pk[j] = cvtpk_bf16(S[0], S[1]);
            }
            const bf16x8 bfrag = __builtin_bit_cast(bf16x8, pk);
            acc[0] = __builtin_amdgcn_mfma_f32_16x16x32_bf16(
                __builtin_bit_cast(bf16x8, wb[sl][ks * 4 + 0]), bfrag, acc[0], 0, 0, 0);
            acc[1] = __builtin_amdgcn_mfma_f32_16x16x32_bf16(
                __builtin_bit_cast(bf16x8, wb[sl][ks * 4 + 1]), bfrag, acc[1], 0, 0, 0);
            acc[2] = __builtin_amdgcn_mfma_f32_16x16x32_bf16(
                __builtin_bit_cast(bf16x8, wb[sl][ks * 4 + 2]), bfrag, acc[2], 0, 0, 0);
            acc[3] = __builtin_amdgcn_mfma_f32_16x16x32_bf16(
                __builtin_bit_cast(bf16x8, wb[sl][ks * 4 + 3]), bfrag, acc[3], 0, 0, 0);
        }
    };

    // ---- software-pipelined 9-tap loop, fence-pinned ----
    prepare(0, 0);
    #pragma unroll
    for (int kt = 0; kt < 9; ++kt) {
        if (kt < 8) prepare(kt + 1, (kt + 1) & 1);    // issue t+1 loads FIRST
        __builtin_amdgcn_sched_barrier(0);            // pin: no sinking past here
        consume(kt & 1);                              // t's loads had a full stage
        __builtin_amdgcn_sched_barrier(0);
    }

    // ---- epilogue: C/D layout col=lane&15 (pixel), row=kq*4+reg (o) ----
    #pragma unroll
    for (int mt = 0; mt < 4; ++mt) {
        const f32x4 bv = *(const f32x4*)(bias + mt * 16 + kq * 4);
        #pragma unroll
        for (int r = 0; r < 4; ++r) {
            const int o = mt * 16 + kq * 4 + r;
            out[((b * 64 + o) * 128 + h) * 128 + wpix] = acc[mt][r] + bv[r];
        }
    }
}

extern "C" void kernel_launch(void* const* d_in, const int* in_sizes, int n_in,
                              void* d_out, int out_size, void* d_ws, size_t ws_size,
                              hipStream_t stream)
{
    const float* input  = (const float*)d_in[0];
    // d_in[1] = depth, unused by the reference
    const float* offset = (const float*)d_in[2];
    const float* mask   = (const float*)d_in[3];
    const float* weight = (const float*)d_in[4];
    const float* bias   = (const float*)d_in[5];
    float* out = (float*)d_out;

    unsigned short* nhwc = (unsigned short*)d_ws;                    // 8.39 MB
    unsigned short* wT2  = nhwc + (size_t)4 * HW * CC;               // 73728 B

    prep_fused19<<<dim3(2066), dim3(256), 0, stream>>>(input, nhwc, weight, wT2);
    ddc_pipe19<<<dim3(512), dim3(512), 0, stream>>>(nhwc, wT2, offset, mask, bias, out);
}